// Round 5
// baseline (230.748 us; speedup 1.0000x reference)
//
#include <hip/hip_runtime.h>
#include <math.h>

#define TT 2048
#define HH 128
#define ROWS 4
#define SP 132   // row-major LDS stride (qs, os)
#define XR 144   // chunk-padded LDS row stride: 4 chunks x 36
#define NBLK (TT / ROWS)

__device__ __forceinline__ float dot4(float4 a, float4 b) {
    return a.x * b.x + a.y * b.y + a.z * b.z + a.w * b.w;
}

// chunk-padded x index: element k of row r lives at r*XR + (k>>5)*36 + (k&31)
__device__ __forceinline__ int xidx(int r, int k) {
    return r * XR + ((k >> 5) * 36) + (k & 31);
}

// ---------------- prep: pack weights [k4][col] column-major + zero barrier ctrs ----
__global__ __launch_bounds__(256) void prep_kernel(
        const float* __restrict__ w_in, const float* __restrict__ w_out,
        const float* __restrict__ w_v, const float* __restrict__ w_q,
        const float* __restrict__ w_k, const float* __restrict__ w_o,
        const float* __restrict__ w_ff,
        float4* __restrict__ win_p, float4* __restrict__ wout_p,
        float4* __restrict__ wcat, float4* __restrict__ wff_p,
        unsigned* __restrict__ bar) {
    int i = blockIdx.x * 256 + threadIdx.x;
    if (blockIdx.x == 0 && threadIdx.x < 16) bar[threadIdx.x] = 0u;
    if (i < 4096) {
        int cg = i >> 7, col = i & 127;
        win_p[i] = ((const float4*)w_in)[col * 32 + cg];
    } else if (i < 8192) {
        int j = i - 4096, cg = j >> 7, col = j & 127;
        wout_p[j] = ((const float4*)w_out)[col * 32 + cg];
    } else if (i < 40960) {
        int j = i - 8192;
        int l = j >> 14, r = j & 16383, cg = r >> 9, col = r & 511;
        int sel = col >> 7, cm = col & 127;
        const float* s = (sel == 0 ? w_v : sel == 1 ? w_q : sel == 2 ? w_k : w_o) + l * HH * HH;
        wcat[j] = ((const float4*)s)[cm * 32 + cg];
    } else {
        int j = i - 40960;
        int l = j >> 13, r = j & 8191, cg = r >> 7, col = r & 127;
        const float* s = w_ff + l * HH * 256;
        wff_p[j] = ((const float4*)s)[col * 64 + cg];
    }
}

// ---- device-wide barrier: 512 blocks, 2/CU guaranteed by __launch_bounds__ cap. ----
__device__ __forceinline__ void grid_barrier(unsigned* __restrict__ ctr) {
    __syncthreads();
    if (threadIdx.x == 0) {
        __threadfence();
        atomicAdd(ctr, 1u);
        while (__hip_atomic_load(ctr, __ATOMIC_RELAXED, __HIP_MEMORY_SCOPE_AGENT)
               < (unsigned)NBLK) {
            __builtin_amdgcn_s_sleep(8);
        }
        __threadfence();
    }
    __syncthreads();
}

// ---- attention (waves 0..ROWS-1): wave wv owns row t0+wv; q,o LDS; k,v,g,i global. ----
__device__ __forceinline__ void attn_row(int t0,
        const float* __restrict__ kb, const float* __restrict__ vb,
        const float* __restrict__ qs, const float* __restrict__ os,
        const float* __restrict__ g, const float* __restrict__ iexp,
        float* __restrict__ hs) {
    int tid = threadIdx.x;
    int wv = tid >> 6, lane = tid & 63;
    if (wv >= ROWS) return;
    int t = t0 + wv;
    float2 q2 = *(const float2*)(qs + wv * SP + 2 * lane);
    float2 o2 = *(const float2*)(os + wv * SP + 2 * lane);
    int tp = t;
    float2 k2 = *(const float2*)(kb + tp * HH + 2 * lane);
    float2 v2 = *(const float2*)(vb + tp * HH + 2 * lane);
    float ie = iexp[tp], gv = g[tp];
    float nx = 0.f, ny = 0.f, dsum = 0.f, decay = 1.f;
    while (true) {
        bool cont = (tp > 0) && (gv != 0.f);
        float2 k2n = {0.f, 0.f}, v2n = {0.f, 0.f};
        float ien = 0.f, gvn = 0.f;
        if (cont) {  // prefetch next step; overlaps the reduce below
            k2n = *(const float2*)(kb + (tp - 1) * HH + 2 * lane);
            v2n = *(const float2*)(vb + (tp - 1) * HH + 2 * lane);
            ien = iexp[tp - 1]; gvn = g[tp - 1];
        }
        float p = k2.x * q2.x + k2.y * q2.y;
#pragma unroll
        for (int off = 1; off <= 32; off <<= 1) p += __shfl_xor(p, off, 64);
        float coeff = decay * ie * p;
        nx += coeff * v2.x; ny += coeff * v2.y; dsum += coeff;
        if (!cont) break;
        decay *= gv;
        tp--; k2 = k2n; v2 = v2n; ie = ien; gv = gvn;
    }
    float inv = 1.f / fmaxf(fabsf(dsum), 1.f);
    int d = 2 * lane;
    *(float2*)(hs + wv * XR + (d >> 5) * 36 + (d & 31)) =
        make_float2(o2.x * nx * inv, o2.y * ny * inv);
}

// ---- f/i scalar gates (waves 0..ROWS-1): wave wv handles row wv. ----
__device__ __forceinline__ void proj_fi(int t0, const float* __restrict__ xls,
        const float* __restrict__ w_f, const float* __restrict__ b_f,
        const float* __restrict__ w_i, const float* __restrict__ b_i,
        const int* __restrict__ start, float* __restrict__ g, float* __restrict__ iexp) {
    int tid = threadIdx.x;
    int wv = tid >> 6, lane = tid & 63;
    if (wv >= ROWS) return;
    int d = 2 * lane;
    float2 xv = *(const float2*)(xls + wv * XR + (d >> 5) * 36 + (d & 31));
    float pf = xv.x * w_f[d] + xv.y * w_f[d + 1];
    float pi = xv.x * w_i[d] + xv.y * w_i[d + 1];
#pragma unroll
    for (int off = 1; off <= 32; off <<= 1) {
        pf += __shfl_xor(pf, off, 64);
        pi += __shfl_xor(pi, off, 64);
    }
    if (lane == 0) {
        int t = t0 + wv;
        g[t] = start[t] ? 0.f : 1.f / (1.f + expf(-(pf + b_f[0])));
        iexp[t] = expf(pi + b_i[0]);
    }
}

// ---- 4 projections, K-split: lane=(kc4,c16), wave wv0-7 -> cslot=wv*16+c (128 cols).
//      Each x4 LDS multicast feeds 4 mats x 4 rows. k,v -> global; q,o -> LDS. ----
__device__ __forceinline__ void proj_block(int t0, const float* __restrict__ xls,
        const float4* __restrict__ wc,
        const float* __restrict__ b_v, const float* __restrict__ b_q,
        const float* __restrict__ b_k, const float* __restrict__ b_o,
        float* __restrict__ kb, float* __restrict__ vb,
        float* __restrict__ qs, float* __restrict__ os) {
    int tid = threadIdx.x;
    int lane = tid & 63, wv = tid >> 6;
    int kc = lane >> 4, c = lane & 15;
    int cslot = wv * 16 + c;
    float acc[4][4] = {};  // [mat][row]
#pragma unroll
    for (int j = 0; j < 8; ++j) {
        const float4* wb = wc + (kc * 8 + j) * 512;
        float4 w0 = wb[cslot];
        float4 w1 = wb[128 + cslot];
        float4 w2 = wb[256 + cslot];
        float4 w3 = wb[384 + cslot];
#pragma unroll
        for (int rr = 0; rr < 4; ++rr) {
            float4 x4 = *(const float4*)(xls + rr * XR + kc * 36 + 4 * j);
            acc[0][rr] += dot4(x4, w0);
            acc[1][rr] += dot4(x4, w1);
            acc[2][rr] += dot4(x4, w2);
            acc[3][rr] += dot4(x4, w3);
        }
    }
#pragma unroll
    for (int m = 0; m < 4; ++m)
#pragma unroll
        for (int rr = 0; rr < 4; ++rr) {
            acc[m][rr] += __shfl_xor(acc[m][rr], 16, 64);
            acc[m][rr] += __shfl_xor(acc[m][rr], 32, 64);
        }
    if (kc == 0) {
        const float ks = 0.088388347648318447f;  // 1/sqrt(128)
        float bv = b_v[cslot], bq = b_q[cslot], bk = b_k[cslot], bo = b_o[cslot];
#pragma unroll
        for (int rr = 0; rr < 4; ++rr) {
            int t = t0 + rr;
            vb[t * HH + cslot] = acc[0][rr] + bv;
            qs[rr * SP + cslot] = acc[1][rr] + bq;
            kb[t * HH + cslot] = acc[2][rr] * ks + bk;
            os[rr * SP + cslot] = 1.f / (1.f + expf(-(acc[3][rr] + bo)));
        }
    }
}

// ---- ff: z = lrelu([h, e] @ w_ff.T + b_ff); 4-way K-split over 256. ----
__device__ __forceinline__ void ff_block(const float* __restrict__ hsb,
        const float* __restrict__ esb, const float4* __restrict__ wff,
        const float* __restrict__ b_ff, float* __restrict__ zs) {
    int tid = threadIdx.x;
    int lane = tid & 63, wv = tid >> 6;
    int kc = lane >> 4, c = lane & 15;
    int cslot = wv * 16 + c;
    const float* xb = (kc < 2) ? hsb : esb;
    int dbase = (kc & 1) * 64;  // within the 128-dim half
    float acc[4] = {};
#pragma unroll
    for (int j = 0; j < 16; ++j) {
        float4 w4 = wff[(kc * 16 + j) * 128 + cslot];
        int d = dbase + 4 * j;
        int off = ((d >> 5) * 36) + (d & 31);
#pragma unroll
        for (int rr = 0; rr < 4; ++rr) {
            float4 x4 = *(const float4*)(xb + rr * XR + off);
            acc[rr] += dot4(x4, w4);
        }
    }
#pragma unroll
    for (int rr = 0; rr < 4; ++rr) {
        acc[rr] += __shfl_xor(acc[rr], 16, 64);
        acc[rr] += __shfl_xor(acc[rr], 32, 64);
    }
    if (kc == 0) {
        float bb = b_ff[cslot];
#pragma unroll
        for (int rr = 0; rr < 4; ++rr) {
            float a = acc[rr] + bb;
            a = a > 0.f ? a : 0.01f * a;
            zs[xidx(rr, cslot)] = a;
        }
    }
}

// ---- 128->128 dense: ys (LDS chunk-padded) or yg (global row-major). ----
__device__ __forceinline__ void dense128(int t0, const float* __restrict__ xls,
        const float4* __restrict__ Wp, const float* __restrict__ b,
        float* __restrict__ yg, float* __restrict__ ys) {
    int tid = threadIdx.x;
    int lane = tid & 63, wv = tid >> 6;
    int kc = lane >> 4, c = lane & 15;
    int cslot = wv * 16 + c;
    float acc[4] = {};
#pragma unroll
    for (int j = 0; j < 8; ++j) {
        float4 w4 = Wp[(kc * 8 + j) * 128 + cslot];
#pragma unroll
        for (int rr = 0; rr < 4; ++rr) {
            float4 x4 = *(const float4*)(xls + rr * XR + kc * 36 + 4 * j);
            acc[rr] += dot4(x4, w4);
        }
    }
#pragma unroll
    for (int rr = 0; rr < 4; ++rr) {
        acc[rr] += __shfl_xor(acc[rr], 16, 64);
        acc[rr] += __shfl_xor(acc[rr], 32, 64);
    }
    if (kc == 0) {
        float bb = b[cslot];
#pragma unroll
        for (int rr = 0; rr < 4; ++rr) {
            float a = acc[rr] + bb;
            if (ys) ys[xidx(rr, cslot)] = a;
            if (yg) yg[(t0 + rr) * HH + cslot] = a;
        }
    }
}

// ---------------- fused: P0 | barrier | P1 | barrier | P2 ----------------
__global__ __launch_bounds__(512, 4) void mega_kernel(
        const float* __restrict__ emb, const int* __restrict__ start,
        const float4* __restrict__ win_p, const float* __restrict__ b_in,
        const float4* __restrict__ wcat,
        const float* __restrict__ b_v, const float* __restrict__ b_q,
        const float* __restrict__ b_k, const float* __restrict__ b_o,
        const float* __restrict__ w_f, const float* __restrict__ b_f,
        const float* __restrict__ w_i, const float* __restrict__ b_i,
        const float4* __restrict__ wff_p, const float* __restrict__ b_ff,
        const float4* __restrict__ wout_p, const float* __restrict__ b_out,
        float* __restrict__ k0b, float* __restrict__ v0b,
        float* __restrict__ k1b, float* __restrict__ v1b,
        float* __restrict__ g0, float* __restrict__ i0,
        float* __restrict__ g1, float* __restrict__ i1,
        unsigned* __restrict__ bar,
        float* __restrict__ out) {
    __shared__ float xs[ROWS * XR];
    __shared__ float es[ROWS * XR];
    __shared__ float hs[ROWS * XR];
    __shared__ float zs[ROWS * XR];
    __shared__ float qs[ROWS * SP];
    __shared__ float os[ROWS * SP];
    int tid = threadIdx.x;
    int t0 = blockIdx.x * ROWS;

    // ---- P0: e (LDS only) + layer-0 projections ----
    {
        int row = tid >> 7, dd = tid & 127;
        xs[row * XR + (dd >> 5) * 36 + (dd & 31)] = emb[(t0 + row) * HH + dd];
    }
    __syncthreads();
    dense128(t0, xs, win_p, b_in, (float*)0, es);
    __syncthreads();
    proj_block(t0, es, wcat, b_v, b_q, b_k, b_o, k0b, v0b, qs, os);
    proj_fi(t0, es, w_f, b_f, w_i, b_i, start, g0, i0);
    grid_barrier(bar + 0);

    // ---- P1: attn0 + ff0 + layer-1 projections ----
    attn_row(t0, k0b, v0b, qs, os, g0, i0, hs);
    __syncthreads();
    ff_block(hs, es, wff_p, b_ff, zs);
    __syncthreads();
    proj_block(t0, zs, wcat + 16384, b_v + HH, b_q + HH, b_k + HH, b_o + HH,
               k1b, v1b, qs, os);
    proj_fi(t0, zs, w_f + HH, b_f + 1, w_i + HH, b_i + 1, start, g1, i1);
    grid_barrier(bar + 1);

    // ---- P2: attn1 + ff1 + final dense ----
    attn_row(t0, k1b, v1b, qs, os, g1, i1, hs);
    __syncthreads();
    ff_block(hs, es, wff_p + 8192, b_ff + HH, zs);
    __syncthreads();
    dense128(t0, zs, wout_p, b_out, out, (float*)0);
}

extern "C" void kernel_launch(void* const* d_in, const int* in_sizes, int n_in,
                              void* d_out, int out_size, void* d_ws, size_t ws_size,
                              hipStream_t stream) {
    const float* emb   = (const float*)d_in[0];
    const int*   start = (const int*)  d_in[1];
    const float* w_in  = (const float*)d_in[2];
    const float* b_in  = (const float*)d_in[3];
    const float* w_out = (const float*)d_in[4];
    const float* b_out = (const float*)d_in[5];
    const float* w_f   = (const float*)d_in[6];
    const float* b_f   = (const float*)d_in[7];
    const float* w_i   = (const float*)d_in[8];
    const float* b_i   = (const float*)d_in[9];
    const float* w_v   = (const float*)d_in[10];
    const float* b_v   = (const float*)d_in[11];
    const float* w_q   = (const float*)d_in[12];
    const float* b_q   = (const float*)d_in[13];
    const float* w_k   = (const float*)d_in[14];
    const float* b_k   = (const float*)d_in[15];
    const float* w_o   = (const float*)d_in[16];
    const float* b_o   = (const float*)d_in[17];
    const float* w_ff  = (const float*)d_in[18];
    const float* b_ff  = (const float*)d_in[19];
    float* out = (float*)d_out;

    unsigned* bar = (unsigned*)d_ws;            // 16 counters, zeroed by prep
    float* ws = (float*)d_ws + 64;
    float* k0b = ws; ws += TT * HH;
    float* v0b = ws; ws += TT * HH;
    float* k1b = ws; ws += TT * HH;
    float* v1b = ws; ws += TT * HH;
    float* g0  = ws; ws += TT;
    float* i0  = ws; ws += TT;
    float* g1  = ws; ws += TT;
    float* i1  = ws; ws += TT;
    float4* win_p  = (float4*)ws; ws += 16384;   // 4096 float4
    float4* wout_p = (float4*)ws; ws += 16384;   // 4096 float4
    float4* wcat   = (float4*)ws; ws += 131072;  // 32768 float4 (2 layers)
    float4* wff_p  = (float4*)ws; ws += 65536;   // 16384 float4 (2 layers)

    prep_kernel<<<dim3(224), dim3(256), 0, stream>>>(
        w_in, w_out, w_v, w_q, w_k, w_o, w_ff, win_p, wout_p, wcat, wff_p, bar);
    mega_kernel<<<dim3(NBLK), dim3(512), 0, stream>>>(
        emb, start, win_p, b_in, wcat,
        b_v, b_q, b_k, b_o, w_f, b_f, w_i, b_i,
        wff_p, b_ff, wout_p, b_out,
        k0b, v0b, k1b, v1b, g0, i0, g1, i1,
        bar, out);
}

// Round 6
// 164.355 us; speedup vs baseline: 1.4040x; 1.4040x over previous
//
#include <hip/hip_runtime.h>
#include <math.h>

#define TT 2048
#define HH 128
#define ROWS 8
#define SP 132   // row-major LDS stride (qs, os)
#define XR 144   // chunk-padded LDS row stride: 4 chunks x 36
#define NBLK (TT / ROWS)

__device__ __forceinline__ float dot4(float4 a, float4 b) {
    return a.x * b.x + a.y * b.y + a.z * b.z + a.w * b.w;
}

// chunk-padded x index: element k of row r lives at r*XR + (k>>5)*36 + (k&31)
__device__ __forceinline__ int xidx(int r, int k) {
    return r * XR + ((k >> 5) * 36) + (k & 31);
}

// ---------------- prep: pack weights [k4][col] column-major + zero barrier ctrs ----
__global__ __launch_bounds__(256) void prep_kernel(
        const float* __restrict__ w_in, const float* __restrict__ w_out,
        const float* __restrict__ w_v, const float* __restrict__ w_q,
        const float* __restrict__ w_k, const float* __restrict__ w_o,
        const float* __restrict__ w_ff,
        float4* __restrict__ win_p, float4* __restrict__ wout_p,
        float4* __restrict__ wcat, float4* __restrict__ wff_p,
        unsigned* __restrict__ bar) {
    int i = blockIdx.x * 256 + threadIdx.x;
    if (blockIdx.x == 0 && threadIdx.x < 16) bar[threadIdx.x] = 0u;
    if (i < 4096) {
        int cg = i >> 7, col = i & 127;
        win_p[i] = ((const float4*)w_in)[col * 32 + cg];
    } else if (i < 8192) {
        int j = i - 4096, cg = j >> 7, col = j & 127;
        wout_p[j] = ((const float4*)w_out)[col * 32 + cg];
    } else if (i < 40960) {
        int j = i - 8192;
        int l = j >> 14, r = j & 16383, cg = r >> 9, col = r & 511;
        int sel = col >> 7, cm = col & 127;
        const float* s = (sel == 0 ? w_v : sel == 1 ? w_q : sel == 2 ? w_k : w_o) + l * HH * HH;
        wcat[j] = ((const float4*)s)[cm * 32 + cg];
    } else {
        int j = i - 40960;
        int l = j >> 13, r = j & 8191, cg = r >> 7, col = r & 127;
        const float* s = w_ff + l * HH * 256;
        wff_p[j] = ((const float4*)s)[col * 64 + cg];
    }
}

// ---- device-wide barrier: 256 blocks on 256 CUs, all co-resident. ----
__device__ __forceinline__ void grid_barrier(unsigned* __restrict__ ctr) {
    __syncthreads();
    if (threadIdx.x == 0) {
        __threadfence();
        atomicAdd(ctr, 1u);
        while (__hip_atomic_load(ctr, __ATOMIC_RELAXED, __HIP_MEMORY_SCOPE_AGENT)
               < (unsigned)NBLK) {
            __builtin_amdgcn_s_sleep(8);
        }
        __threadfence();
    }
    __syncthreads();
}

// ---- attention: wave wv owns row t0+wv; q,o from LDS row-major; k,v,g,i global. ----
__device__ __forceinline__ void attn_row(int t0,
        const float* __restrict__ kb, const float* __restrict__ vb,
        const float* __restrict__ qs, const float* __restrict__ os,
        const float* __restrict__ g, const float* __restrict__ iexp,
        float* __restrict__ hs) {
    int tid = threadIdx.x;
    int wv = tid >> 6, lane = tid & 63;
    int t = t0 + wv;
    float2 q2 = *(const float2*)(qs + wv * SP + 2 * lane);
    float2 o2 = *(const float2*)(os + wv * SP + 2 * lane);
    int tp = t;
    float2 k2 = *(const float2*)(kb + tp * HH + 2 * lane);
    float2 v2 = *(const float2*)(vb + tp * HH + 2 * lane);
    float ie = iexp[tp], gv = g[tp];
    float nx = 0.f, ny = 0.f, dsum = 0.f, decay = 1.f;
    while (true) {
        bool cont = (tp > 0) && (gv != 0.f);
        float2 k2n = {0.f, 0.f}, v2n = {0.f, 0.f};
        float ien = 0.f, gvn = 0.f;
        if (cont) {  // prefetch next step; overlaps the reduce below
            k2n = *(const float2*)(kb + (tp - 1) * HH + 2 * lane);
            v2n = *(const float2*)(vb + (tp - 1) * HH + 2 * lane);
            ien = iexp[tp - 1]; gvn = g[tp - 1];
        }
        float p = k2.x * q2.x + k2.y * q2.y;
#pragma unroll
        for (int off = 1; off <= 32; off <<= 1) p += __shfl_xor(p, off, 64);
        float coeff = decay * ie * p;
        nx += coeff * v2.x; ny += coeff * v2.y; dsum += coeff;
        if (!cont) break;
        decay *= gv;
        tp--; k2 = k2n; v2 = v2n; ie = ien; gv = gvn;
    }
    float inv = 1.f / fmaxf(fabsf(dsum), 1.f);
    int d = 2 * lane;
    *(float2*)(hs + wv * XR + (d >> 5) * 36 + (d & 31)) =
        make_float2(o2.x * nx * inv, o2.y * ny * inv);
}

// ---- f/i scalar gates: wave wv handles row wv; x in chunk-padded layout. ----
__device__ __forceinline__ void proj_fi(int t0, const float* __restrict__ xls,
        const float* __restrict__ w_f, const float* __restrict__ b_f,
        const float* __restrict__ w_i, const float* __restrict__ b_i,
        const int* __restrict__ start, float* __restrict__ g, float* __restrict__ iexp) {
    int tid = threadIdx.x;
    int wv = tid >> 6, lane = tid & 63;
    int d = 2 * lane;
    float2 xv = *(const float2*)(xls + wv * XR + (d >> 5) * 36 + (d & 31));
    float pf = xv.x * w_f[d] + xv.y * w_f[d + 1];
    float pi = xv.x * w_i[d] + xv.y * w_i[d + 1];
#pragma unroll
    for (int off = 1; off <= 32; off <<= 1) {
        pf += __shfl_xor(pf, off, 64);
        pi += __shfl_xor(pi, off, 64);
    }
    if (lane == 0) {
        int t = t0 + wv;
        g[t] = start[t] ? 0.f : 1.f / (1.f + expf(-(pf + b_f[0])));
        iexp[t] = expf(pi + b_i[0]);
    }
}

// ---- software-pipelined 32-k-chunk GEMV: 2 cols (cslot, cslot+64), 4 rows. ----
__device__ __forceinline__ void gemv_chunk_pipe(const float* __restrict__ xb,
        const float4* __restrict__ Wp, int k4base, int cslot, float acc[2][4]) {
    float4 wA0 = Wp[k4base * 128 + cslot];
    float4 wA1 = Wp[k4base * 128 + 64 + cslot];
    float4 xA0 = *(const float4*)(xb + 0 * XR);
    float4 xA1 = *(const float4*)(xb + 1 * XR);
    float4 xA2 = *(const float4*)(xb + 2 * XR);
    float4 xA3 = *(const float4*)(xb + 3 * XR);
    float4 wB0, wB1, xB0, xB1, xB2, xB3;
#pragma unroll
    for (int j = 0; j < 8; j += 2) {
        wB0 = Wp[(k4base + j + 1) * 128 + cslot];
        wB1 = Wp[(k4base + j + 1) * 128 + 64 + cslot];
        xB0 = *(const float4*)(xb + 0 * XR + 4 * (j + 1));
        xB1 = *(const float4*)(xb + 1 * XR + 4 * (j + 1));
        xB2 = *(const float4*)(xb + 2 * XR + 4 * (j + 1));
        xB3 = *(const float4*)(xb + 3 * XR + 4 * (j + 1));
        acc[0][0] += dot4(xA0, wA0); acc[1][0] += dot4(xA0, wA1);
        acc[0][1] += dot4(xA1, wA0); acc[1][1] += dot4(xA1, wA1);
        acc[0][2] += dot4(xA2, wA0); acc[1][2] += dot4(xA2, wA1);
        acc[0][3] += dot4(xA3, wA0); acc[1][3] += dot4(xA3, wA1);
        if (j + 2 < 8) {
            wA0 = Wp[(k4base + j + 2) * 128 + cslot];
            wA1 = Wp[(k4base + j + 2) * 128 + 64 + cslot];
            xA0 = *(const float4*)(xb + 0 * XR + 4 * (j + 2));
            xA1 = *(const float4*)(xb + 1 * XR + 4 * (j + 2));
            xA2 = *(const float4*)(xb + 2 * XR + 4 * (j + 2));
            xA3 = *(const float4*)(xb + 3 * XR + 4 * (j + 2));
        }
        acc[0][0] += dot4(xB0, wB0); acc[1][0] += dot4(xB0, wB1);
        acc[0][1] += dot4(xB1, wB0); acc[1][1] += dot4(xB1, wB1);
        acc[0][2] += dot4(xB2, wB0); acc[1][2] += dot4(xB2, wB1);
        acc[0][3] += dot4(xB3, wB0); acc[1][3] += dot4(xB3, wB1);
    }
}

// ---- 4 projections fused, K-split, pipelined: k,v -> global; q,o -> LDS. ----
__device__ __forceinline__ void proj_block(int t0, const float* __restrict__ xls,
        const float4* __restrict__ wc,
        const float* __restrict__ b_v, const float* __restrict__ b_q,
        const float* __restrict__ b_k, const float* __restrict__ b_o,
        float* __restrict__ kb, float* __restrict__ vb,
        float* __restrict__ qs, float* __restrict__ os) {
    int tid = threadIdx.x;
    int lane = tid & 63, wv = tid >> 6;
    int kc = lane >> 4, c = lane & 15;
    int rg = wv >> 2, cslot = (wv & 3) * 16 + c;
    const float* xb = xls + (rg * 4) * XR + kc * 36;
    float acc[4][2][4] = {};
    float4 wA[4][2], wB[4][2], xA[4], xB[4];
    {
        const float4* wb0 = wc + (kc * 8) * 512;
#pragma unroll
        for (int m = 0; m < 4; ++m) {
            wA[m][0] = wb0[m * 128 + cslot];
            wA[m][1] = wb0[m * 128 + 64 + cslot];
        }
#pragma unroll
        for (int rr = 0; rr < 4; ++rr) xA[rr] = *(const float4*)(xb + rr * XR);
    }
#pragma unroll
    for (int j = 0; j < 8; j += 2) {
        const float4* wbn = wc + (kc * 8 + j + 1) * 512;
#pragma unroll
        for (int m = 0; m < 4; ++m) {
            wB[m][0] = wbn[m * 128 + cslot];
            wB[m][1] = wbn[m * 128 + 64 + cslot];
        }
#pragma unroll
        for (int rr = 0; rr < 4; ++rr)
            xB[rr] = *(const float4*)(xb + rr * XR + 4 * (j + 1));
#pragma unroll
        for (int rr = 0; rr < 4; ++rr)
#pragma unroll
            for (int m = 0; m < 4; ++m) {
                acc[m][0][rr] += dot4(xA[rr], wA[m][0]);
                acc[m][1][rr] += dot4(xA[rr], wA[m][1]);
            }
        if (j + 2 < 8) {
            const float4* wbn2 = wc + (kc * 8 + j + 2) * 512;
#pragma unroll
            for (int m = 0; m < 4; ++m) {
                wA[m][0] = wbn2[m * 128 + cslot];
                wA[m][1] = wbn2[m * 128 + 64 + cslot];
            }
#pragma unroll
            for (int rr = 0; rr < 4; ++rr)
                xA[rr] = *(const float4*)(xb + rr * XR + 4 * (j + 2));
        }
#pragma unroll
        for (int rr = 0; rr < 4; ++rr)
#pragma unroll
            for (int m = 0; m < 4; ++m) {
                acc[m][0][rr] += dot4(xB[rr], wB[m][0]);
                acc[m][1][rr] += dot4(xB[rr], wB[m][1]);
            }
    }
#pragma unroll
    for (int m = 0; m < 4; ++m)
#pragma unroll
        for (int h = 0; h < 2; ++h)
#pragma unroll
            for (int rr = 0; rr < 4; ++rr) {
                acc[m][h][rr] += __shfl_xor(acc[m][h][rr], 16, 64);
                acc[m][h][rr] += __shfl_xor(acc[m][h][rr], 32, 64);
            }
    if (kc == 0) {
        const float ks = 0.088388347648318447f;  // 1/sqrt(128)
#pragma unroll
        for (int h = 0; h < 2; ++h) {
            int col = cslot + 64 * h;
            float bv = b_v[col], bq = b_q[col], bk = b_k[col], bo = b_o[col];
#pragma unroll
            for (int rr = 0; rr < 4; ++rr) {
                int r = rg * 4 + rr, t = t0 + r;
                vb[t * HH + col] = acc[0][h][rr] + bv;
                qs[r * SP + col] = acc[1][h][rr] + bq;
                kb[t * HH + col] = acc[2][h][rr] * ks + bk;
                os[r * SP + col] = 1.f / (1.f + expf(-(acc[3][h][rr] + bo)));
            }
        }
    }
}

// ---- ff: z = lrelu([h, e] @ w_ff.T + b_ff) -> zs chunk-padded. ----
__device__ __forceinline__ void ff_block(const float* __restrict__ hsb,
        const float* __restrict__ esb, const float4* __restrict__ wff,
        const float* __restrict__ b_ff, float* __restrict__ zs) {
    int tid = threadIdx.x;
    int lane = tid & 63, wv = tid >> 6;
    int kc = lane >> 4, c = lane & 15;
    int rg = wv >> 2, cslot = (wv & 3) * 16 + c;
    float acc[2][4] = {};
    gemv_chunk_pipe(hsb + rg * 4 * XR + kc * 36, wff, kc * 8, cslot, acc);
    gemv_chunk_pipe(esb + rg * 4 * XR + kc * 36, wff, 32 + kc * 8, cslot, acc);
#pragma unroll
    for (int h = 0; h < 2; ++h)
#pragma unroll
        for (int rr = 0; rr < 4; ++rr) {
            acc[h][rr] += __shfl_xor(acc[h][rr], 16, 64);
            acc[h][rr] += __shfl_xor(acc[h][rr], 32, 64);
        }
    if (kc == 0) {
#pragma unroll
        for (int h = 0; h < 2; ++h) {
            int col = cslot + 64 * h;
            float bb = b_ff[col];
#pragma unroll
            for (int rr = 0; rr < 4; ++rr) {
                int r = rg * 4 + rr;
                float a = acc[h][rr] + bb;
                a = a > 0.f ? a : 0.01f * a;
                zs[xidx(r, col)] = a;
            }
        }
    }
}

// ---- 128->128 dense: ys (LDS chunk-padded) or yg (global row-major). ----
__device__ __forceinline__ void dense128(int t0, const float* __restrict__ xls,
        const float4* __restrict__ Wp, const float* __restrict__ b,
        float* __restrict__ yg, float* __restrict__ ys) {
    int tid = threadIdx.x;
    int lane = tid & 63, wv = tid >> 6;
    int kc = lane >> 4, c = lane & 15;
    int rg = wv >> 2, cslot = (wv & 3) * 16 + c;
    float acc[2][4] = {};
    gemv_chunk_pipe(xls + rg * 4 * XR + kc * 36, Wp, kc * 8, cslot, acc);
#pragma unroll
    for (int h = 0; h < 2; ++h)
#pragma unroll
        for (int rr = 0; rr < 4; ++rr) {
            acc[h][rr] += __shfl_xor(acc[h][rr], 16, 64);
            acc[h][rr] += __shfl_xor(acc[h][rr], 32, 64);
        }
    if (kc == 0) {
#pragma unroll
        for (int h = 0; h < 2; ++h) {
            int col = cslot + 64 * h;
            float bb = b[col];
#pragma unroll
            for (int rr = 0; rr < 4; ++rr) {
                int r = rg * 4 + rr;
                float a = acc[h][rr] + bb;
                if (ys) ys[xidx(r, col)] = a;
                if (yg) yg[(t0 + r) * HH + col] = a;
            }
        }
    }
}

// ---------------- fused: P0 | barrier | P1 | barrier | P2 ----------------
__global__ __launch_bounds__(512, 2) void mega_kernel(
        const float* __restrict__ emb, const int* __restrict__ start,
        const float4* __restrict__ win_p, const float* __restrict__ b_in,
        const float4* __restrict__ wcat,
        const float* __restrict__ b_v, const float* __restrict__ b_q,
        const float* __restrict__ b_k, const float* __restrict__ b_o,
        const float* __restrict__ w_f, const float* __restrict__ b_f,
        const float* __restrict__ w_i, const float* __restrict__ b_i,
        const float4* __restrict__ wff_p, const float* __restrict__ b_ff,
        const float4* __restrict__ wout_p, const float* __restrict__ b_out,
        float* __restrict__ k0b, float* __restrict__ v0b,
        float* __restrict__ k1b, float* __restrict__ v1b,
        float* __restrict__ g0, float* __restrict__ i0,
        float* __restrict__ g1, float* __restrict__ i1,
        unsigned* __restrict__ bar,
        float* __restrict__ out) {
    __shared__ float xs[ROWS * XR];
    __shared__ float es[ROWS * XR];
    __shared__ float hs[ROWS * XR];
    __shared__ float zs[ROWS * XR];
    __shared__ float qs[ROWS * SP];
    __shared__ float os[ROWS * SP];
    int tid = threadIdx.x;
    int t0 = blockIdx.x * ROWS;
    int wv = tid >> 6, lane = tid & 63;
    int d = 2 * lane;

    // ---- P0 ----
    float2 ev = *(const float2*)(emb + (t0 + wv) * HH + d);
    *(float2*)(xs + wv * XR + (d >> 5) * 36 + (d & 31)) = ev;
    __syncthreads();
    dense128(t0, xs, win_p, b_in, (float*)0, es);
    __syncthreads();
    proj_block(t0, es, wcat, b_v, b_q, b_k, b_o, k0b, v0b, qs, os);
    proj_fi(t0, es, w_f, b_f, w_i, b_i, start, g0, i0);
    grid_barrier(bar + 0);

    // ---- P1 ----
    attn_row(t0, k0b, v0b, qs, os, g0, i0, hs);
    __syncthreads();
    ff_block(hs, es, wff_p, b_ff, zs);
    __syncthreads();
    proj_block(t0, zs, wcat + 16384, b_v + HH, b_q + HH, b_k + HH, b_o + HH,
               k1b, v1b, qs, os);
    proj_fi(t0, zs, w_f + HH, b_f + 1, w_i + HH, b_i + 1, start, g1, i1);
    grid_barrier(bar + 1);

    // ---- P2 ----
    attn_row(t0, k1b, v1b, qs, os, g1, i1, hs);
    __syncthreads();
    ff_block(hs, es, wff_p + 8192, b_ff + HH, zs);
    __syncthreads();
    dense128(t0, zs, wout_p, b_out, out, (float*)0);
}

extern "C" void kernel_launch(void* const* d_in, const int* in_sizes, int n_in,
                              void* d_out, int out_size, void* d_ws, size_t ws_size,
                              hipStream_t stream) {
    const float* emb   = (const float*)d_in[0];
    const int*   start = (const int*)  d_in[1];
    const float* w_in  = (const float*)d_in[2];
    const float* b_in  = (const float*)d_in[3];
    const float* w_out = (const float*)d_in[4];
    const float* b_out = (const float*)d_in[5];
    const float* w_f   = (const float*)d_in[6];
    const float* b_f   = (const float*)d_in[7];
    const float* w_i   = (const float*)d_in[8];
    const float* b_i   = (const float*)d_in[9];
    const float* w_v   = (const float*)d_in[10];
    const float* b_v   = (const float*)d_in[11];
    const float* w_q   = (const float*)d_in[12];
    const float* b_q   = (const float*)d_in[13];
    const float* w_k   = (const float*)d_in[14];
    const float* b_k   = (const float*)d_in[15];
    const float* w_o   = (const float*)d_in[16];
    const float* b_o   = (const float*)d_in[17];
    const float* w_ff  = (const float*)d_in[18];
    const float* b_ff  = (const float*)d_in[19];
    float* out = (float*)d_out;

    unsigned* bar = (unsigned*)d_ws;            // 16 counters, zeroed by prep
    float* ws = (float*)d_ws + 64;
    float* k0b = ws; ws += TT * HH;
    float* v0b = ws; ws += TT * HH;
    float* k1b = ws; ws += TT * HH;
    float* v1b = ws; ws += TT * HH;
    float* g0  = ws; ws += TT;
    float* i0  = ws; ws += TT;
    float* g1  = ws; ws += TT;
    float* i1  = ws; ws += TT;
    float4* win_p  = (float4*)ws; ws += 16384;   // 4096 float4
    float4* wout_p = (float4*)ws; ws += 16384;   // 4096 float4
    float4* wcat   = (float4*)ws; ws += 131072;  // 32768 float4 (2 layers)
    float4* wff_p  = (float4*)ws; ws += 65536;   // 16384 float4 (2 layers)

    prep_kernel<<<dim3(224), dim3(256), 0, stream>>>(
        w_in, w_out, w_v, w_q, w_k, w_o, w_ff, win_p, wout_p, wcat, wff_p, bar);
    mega_kernel<<<dim3(NBLK), dim3(512), 0, stream>>>(
        emb, start, win_p, b_in, wcat,
        b_v, b_q, b_k, b_o, w_f, b_f, w_i, b_i,
        wff_p, b_ff, wout_p, b_out,
        k0b, v0b, k1b, v1b, g0, i0, g1, i1,
        bar, out);
}

// Round 7
// 143.708 us; speedup vs baseline: 1.6057x; 1.1437x over previous
//
#include <hip/hip_runtime.h>
#include <math.h>

#define TT 2048
#define HH 128
#define ROWS 8
#define SP 132   // row-major LDS stride (qs, os)
#define XR 144   // chunk-padded LDS row stride: 4 chunks x 36
#define NBLK (TT / ROWS)

__device__ __forceinline__ float dot4(float4 a, float4 b) {
    return a.x * b.x + a.y * b.y + a.z * b.z + a.w * b.w;
}

// chunk-padded x index: element k of row r lives at r*XR + (k>>5)*36 + (k&31)
__device__ __forceinline__ int xidx(int r, int k) {
    return r * XR + ((k >> 5) * 36) + (k & 31);
}

// ---- agent-scope (cross-XCD coherent, L1/L2-bypassing) accessors for kv/gi ----
__device__ __forceinline__ float2 load_f2_agent(const float* p) {
    unsigned long long u = __hip_atomic_load((const unsigned long long*)p,
                                             __ATOMIC_RELAXED, __HIP_MEMORY_SCOPE_AGENT);
    float2 r;
    r.x = __uint_as_float((unsigned)(u & 0xffffffffull));
    r.y = __uint_as_float((unsigned)(u >> 32));
    return r;
}
__device__ __forceinline__ float load_f_agent(const float* p) {
    return __hip_atomic_load(p, __ATOMIC_RELAXED, __HIP_MEMORY_SCOPE_AGENT);
}
__device__ __forceinline__ void store_f_agent(float* p, float v) {
    __hip_atomic_store(p, v, __ATOMIC_RELAXED, __HIP_MEMORY_SCOPE_AGENT);
}

// ---------------- prep: pack weights [k4][col] column-major + zero barrier ctrs ----
__global__ __launch_bounds__(256) void prep_kernel(
        const float* __restrict__ w_in, const float* __restrict__ w_out,
        const float* __restrict__ w_v, const float* __restrict__ w_q,
        const float* __restrict__ w_k, const float* __restrict__ w_o,
        const float* __restrict__ w_ff,
        float4* __restrict__ win_p, float4* __restrict__ wout_p,
        float4* __restrict__ wcat, float4* __restrict__ wff_p,
        unsigned* __restrict__ bar) {
    int i = blockIdx.x * 256 + threadIdx.x;
    if (blockIdx.x == 0 && threadIdx.x < 16) bar[threadIdx.x] = 0u;
    if (i < 4096) {
        int cg = i >> 7, col = i & 127;
        win_p[i] = ((const float4*)w_in)[col * 32 + cg];
    } else if (i < 8192) {
        int j = i - 4096, cg = j >> 7, col = j & 127;
        wout_p[j] = ((const float4*)w_out)[col * 32 + cg];
    } else if (i < 40960) {
        int j = i - 8192;
        int l = j >> 14, r = j & 16383, cg = r >> 9, col = r & 511;
        int sel = col >> 7, cm = col & 127;
        const float* s = (sel == 0 ? w_v : sel == 1 ? w_q : sel == 2 ? w_k : w_o) + l * HH * HH;
        wcat[j] = ((const float4*)s)[cm * 32 + cg];
    } else {
        int j = i - 40960;
        int l = j >> 13, r = j & 8191, cg = r >> 7, col = r & 127;
        const float* s = w_ff + l * HH * 256;
        wff_p[j] = ((const float4*)s)[col * 64 + cg];
    }
}

// ---- device-wide barrier WITHOUT agent fences (no L2 wb/inv — weights stay warm).
// Cross-block data (kv/gi) moves via agent-scope atomics that bypass L1/L2, so the
// only ordering needed is: all stores complete (vmcnt0 at __syncthreads) -> arrive.
__device__ __forceinline__ void grid_barrier(unsigned* __restrict__ ctr) {
    __syncthreads();  // compiler emits s_waitcnt vmcnt(0) lgkmcnt(0) before s_barrier
    if (threadIdx.x == 0) {
        atomicAdd(ctr, 1u);  // device-scope atomic, coherent at L3
        while (__hip_atomic_load(ctr, __ATOMIC_RELAXED, __HIP_MEMORY_SCOPE_AGENT)
               < (unsigned)NBLK) {
            __builtin_amdgcn_s_sleep(8);
        }
    }
    __syncthreads();
}

// ---- attention: wave wv owns row t0+wv; q,o from LDS; k,v,g,i via agent loads. ----
__device__ __forceinline__ void attn_row(int t0,
        const float* __restrict__ kb, const float* __restrict__ vb,
        const float* __restrict__ qs, const float* __restrict__ os,
        const float* __restrict__ g, const float* __restrict__ iexp,
        float* __restrict__ hs) {
    int tid = threadIdx.x;
    int wv = tid >> 6, lane = tid & 63;
    int t = t0 + wv;
    float2 q2 = *(const float2*)(qs + wv * SP + 2 * lane);
    float2 o2 = *(const float2*)(os + wv * SP + 2 * lane);
    int tp = t;
    float2 k2 = load_f2_agent(kb + tp * HH + 2 * lane);
    float2 v2 = load_f2_agent(vb + tp * HH + 2 * lane);
    float ie = load_f_agent(iexp + tp), gv = load_f_agent(g + tp);
    float nx = 0.f, ny = 0.f, dsum = 0.f, decay = 1.f;
    while (true) {
        bool cont = (tp > 0) && (gv != 0.f);
        float2 k2n = {0.f, 0.f}, v2n = {0.f, 0.f};
        float ien = 0.f, gvn = 0.f;
        if (cont) {  // prefetch next step; overlaps the reduce below
            k2n = load_f2_agent(kb + (tp - 1) * HH + 2 * lane);
            v2n = load_f2_agent(vb + (tp - 1) * HH + 2 * lane);
            ien = load_f_agent(iexp + tp - 1); gvn = load_f_agent(g + tp - 1);
        }
        float p = k2.x * q2.x + k2.y * q2.y;
#pragma unroll
        for (int off = 1; off <= 32; off <<= 1) p += __shfl_xor(p, off, 64);
        float coeff = decay * ie * p;
        nx += coeff * v2.x; ny += coeff * v2.y; dsum += coeff;
        if (!cont) break;
        decay *= gv;
        tp--; k2 = k2n; v2 = v2n; ie = ien; gv = gvn;
    }
    float inv = 1.f / fmaxf(fabsf(dsum), 1.f);
    int d = 2 * lane;
    *(float2*)(hs + wv * XR + (d >> 5) * 36 + (d & 31)) =
        make_float2(o2.x * nx * inv, o2.y * ny * inv);
}

// ---- f/i scalar gates: wave wv handles row wv; agent stores to g/iexp. ----
__device__ __forceinline__ void proj_fi(int t0, const float* __restrict__ xls,
        const float* __restrict__ w_f, const float* __restrict__ b_f,
        const float* __restrict__ w_i, const float* __restrict__ b_i,
        const int* __restrict__ start, float* __restrict__ g, float* __restrict__ iexp) {
    int tid = threadIdx.x;
    int wv = tid >> 6, lane = tid & 63;
    int d = 2 * lane;
    float2 xv = *(const float2*)(xls + wv * XR + (d >> 5) * 36 + (d & 31));
    float pf = xv.x * w_f[d] + xv.y * w_f[d + 1];
    float pi = xv.x * w_i[d] + xv.y * w_i[d + 1];
#pragma unroll
    for (int off = 1; off <= 32; off <<= 1) {
        pf += __shfl_xor(pf, off, 64);
        pi += __shfl_xor(pi, off, 64);
    }
    if (lane == 0) {
        int t = t0 + wv;
        store_f_agent(g + t, start[t] ? 0.f : 1.f / (1.f + expf(-(pf + b_f[0]))));
        store_f_agent(iexp + t, expf(pi + b_i[0]));
    }
}

// ---- 4 projections fused, K-split: k,v -> agent stores; q,o -> LDS. ----
__device__ __forceinline__ void proj_block(int t0, const float* __restrict__ xls,
        const float4* __restrict__ wc,
        const float* __restrict__ b_v, const float* __restrict__ b_q,
        const float* __restrict__ b_k, const float* __restrict__ b_o,
        float* __restrict__ kb, float* __restrict__ vb,
        float* __restrict__ qs, float* __restrict__ os) {
    int tid = threadIdx.x;
    int lane = tid & 63, wv = tid >> 6;
    int kc = lane >> 4, c = lane & 15;
    int rg = wv >> 2, cslot = (wv & 3) * 16 + c;
    float acc[4][4] = {};  // [mat][row] for 2 h-halves sequential below
    float acc2[4][4] = {};
#pragma unroll
    for (int j = 0; j < 8; ++j) {
        const float4* wb = wc + (kc * 8 + j) * 512;
        float4 w0 = wb[cslot];
        float4 w1 = wb[128 + cslot];
        float4 w2 = wb[256 + cslot];
        float4 w3 = wb[384 + cslot];
        float4 w0h = wb[64 + cslot];
        float4 w1h = wb[192 + cslot];
        float4 w2h = wb[320 + cslot];
        float4 w3h = wb[448 + cslot];
#pragma unroll
        for (int rr = 0; rr < 4; ++rr) {
            float4 x4 = *(const float4*)(xls + (rg * 4 + rr) * XR + kc * 36 + 4 * j);
            acc[0][rr] += dot4(x4, w0);
            acc[1][rr] += dot4(x4, w1);
            acc[2][rr] += dot4(x4, w2);
            acc[3][rr] += dot4(x4, w3);
            acc2[0][rr] += dot4(x4, w0h);
            acc2[1][rr] += dot4(x4, w1h);
            acc2[2][rr] += dot4(x4, w2h);
            acc2[3][rr] += dot4(x4, w3h);
        }
    }
#pragma unroll
    for (int m = 0; m < 4; ++m)
#pragma unroll
        for (int rr = 0; rr < 4; ++rr) {
            acc[m][rr] += __shfl_xor(acc[m][rr], 16, 64);
            acc[m][rr] += __shfl_xor(acc[m][rr], 32, 64);
            acc2[m][rr] += __shfl_xor(acc2[m][rr], 16, 64);
            acc2[m][rr] += __shfl_xor(acc2[m][rr], 32, 64);
        }
    if (kc == 0) {
        const float ks = 0.088388347648318447f;  // 1/sqrt(128)
#pragma unroll
        for (int h = 0; h < 2; ++h) {
            int col = cslot + 64 * h;
            float bv = b_v[col], bq = b_q[col], bk = b_k[col], bo = b_o[col];
#pragma unroll
            for (int rr = 0; rr < 4; ++rr) {
                int r = rg * 4 + rr, t = t0 + r;
                float av = (h == 0 ? acc[0][rr] : acc2[0][rr]);
                float aq = (h == 0 ? acc[1][rr] : acc2[1][rr]);
                float ak = (h == 0 ? acc[2][rr] : acc2[2][rr]);
                float ao = (h == 0 ? acc[3][rr] : acc2[3][rr]);
                store_f_agent(vb + t * HH + col, av + bv);
                qs[r * SP + col] = aq + bq;
                store_f_agent(kb + t * HH + col, ak * ks + bk);
                os[r * SP + col] = 1.f / (1.f + expf(-(ao + bo)));
            }
        }
    }
}

// ---- K-split GEMV core (N=128) over one 32-k chunk. ----
__device__ __forceinline__ void gemv128(int rg, int kc, int cslot,
        const float* __restrict__ xs, const float4* __restrict__ Wp, int k4base,
        float acc[2][4]) {
#pragma unroll
    for (int j = 0; j < 8; ++j) {
        int k4 = k4base + kc * 8 + j;
        float4 w0 = Wp[k4 * 128 + cslot];
        float4 w1 = Wp[k4 * 128 + 64 + cslot];
#pragma unroll
        for (int rr = 0; rr < 4; ++rr) {
            float4 x4 = *(const float4*)(xs + (rg * 4 + rr) * XR + kc * 36 + 4 * j);
            acc[0][rr] += dot4(x4, w0);
            acc[1][rr] += dot4(x4, w1);
        }
    }
}

// ---- ff: z = lrelu([h, e] @ w_ff.T + b_ff) -> zs chunk-padded. ----
__device__ __forceinline__ void ff_block(const float* __restrict__ hsb,
        const float* __restrict__ esb, const float4* __restrict__ wff,
        const float* __restrict__ b_ff, float* __restrict__ zs) {
    int tid = threadIdx.x;
    int lane = tid & 63, wv = tid >> 6;
    int kc = lane >> 4, c = lane & 15;
    int rg = wv >> 2, cslot = (wv & 3) * 16 + c;
    float acc[2][4] = {};
    gemv128(rg, kc, cslot, hsb, wff, 0, acc);
    gemv128(rg, kc, cslot, esb, wff, 32, acc);
#pragma unroll
    for (int h = 0; h < 2; ++h)
#pragma unroll
        for (int rr = 0; rr < 4; ++rr) {
            acc[h][rr] += __shfl_xor(acc[h][rr], 16, 64);
            acc[h][rr] += __shfl_xor(acc[h][rr], 32, 64);
        }
    if (kc == 0) {
#pragma unroll
        for (int h = 0; h < 2; ++h) {
            int col = cslot + 64 * h;
            float bb = b_ff[col];
#pragma unroll
            for (int rr = 0; rr < 4; ++rr) {
                int r = rg * 4 + rr;
                float a = acc[h][rr] + bb;
                a = a > 0.f ? a : 0.01f * a;
                zs[xidx(r, col)] = a;
            }
        }
    }
}

// ---- 128->128 dense: ys (LDS chunk-padded) or yg (global row-major). ----
__device__ __forceinline__ void dense128(int t0, const float* __restrict__ xls,
        const float4* __restrict__ Wp, const float* __restrict__ b,
        float* __restrict__ yg, float* __restrict__ ys) {
    int tid = threadIdx.x;
    int lane = tid & 63, wv = tid >> 6;
    int kc = lane >> 4, c = lane & 15;
    int rg = wv >> 2, cslot = (wv & 3) * 16 + c;
    float acc[2][4] = {};
    gemv128(rg, kc, cslot, xls, Wp, 0, acc);
#pragma unroll
    for (int h = 0; h < 2; ++h)
#pragma unroll
        for (int rr = 0; rr < 4; ++rr) {
            acc[h][rr] += __shfl_xor(acc[h][rr], 16, 64);
            acc[h][rr] += __shfl_xor(acc[h][rr], 32, 64);
        }
    if (kc == 0) {
#pragma unroll
        for (int h = 0; h < 2; ++h) {
            int col = cslot + 64 * h;
            float bb = b[col];
#pragma unroll
            for (int rr = 0; rr < 4; ++rr) {
                int r = rg * 4 + rr;
                float a = acc[h][rr] + bb;
                if (ys) ys[xidx(r, col)] = a;
                if (yg) yg[(t0 + r) * HH + col] = a;
            }
        }
    }
}

// ---------------- fused: P0 | barrier | P1 | barrier | P2 ----------------
__global__ __launch_bounds__(512, 2) void mega_kernel(
        const float* __restrict__ emb, const int* __restrict__ start,
        const float4* __restrict__ win_p, const float* __restrict__ b_in,
        const float4* __restrict__ wcat,
        const float* __restrict__ b_v, const float* __restrict__ b_q,
        const float* __restrict__ b_k, const float* __restrict__ b_o,
        const float* __restrict__ w_f, const float* __restrict__ b_f,
        const float* __restrict__ w_i, const float* __restrict__ b_i,
        const float4* __restrict__ wff_p, const float* __restrict__ b_ff,
        const float4* __restrict__ wout_p, const float* __restrict__ b_out,
        float* __restrict__ k0b, float* __restrict__ v0b,
        float* __restrict__ k1b, float* __restrict__ v1b,
        float* __restrict__ g0, float* __restrict__ i0,
        float* __restrict__ g1, float* __restrict__ i1,
        unsigned* __restrict__ bar,
        float* __restrict__ out) {
    __shared__ float xs[ROWS * XR];
    __shared__ float es[ROWS * XR];
    __shared__ float hs[ROWS * XR];
    __shared__ float zs[ROWS * XR];
    __shared__ float qs[ROWS * SP];
    __shared__ float os[ROWS * SP];
    int tid = threadIdx.x;
    int t0 = blockIdx.x * ROWS;
    int wv = tid >> 6, lane = tid & 63;
    int d = 2 * lane;

    // ---- P0 ----
    float2 ev = *(const float2*)(emb + (t0 + wv) * HH + d);
    *(float2*)(xs + wv * XR + (d >> 5) * 36 + (d & 31)) = ev;
    __syncthreads();
    dense128(t0, xs, win_p, b_in, (float*)0, es);
    __syncthreads();
    proj_block(t0, es, wcat, b_v, b_q, b_k, b_o, k0b, v0b, qs, os);
    proj_fi(t0, es, w_f, b_f, w_i, b_i, start, g0, i0);
    grid_barrier(bar + 0);

    // ---- P1 ----
    attn_row(t0, k0b, v0b, qs, os, g0, i0, hs);
    __syncthreads();
    ff_block(hs, es, wff_p, b_ff, zs);
    __syncthreads();
    proj_block(t0, zs, wcat + 16384, b_v + HH, b_q + HH, b_k + HH, b_o + HH,
               k1b, v1b, qs, os);
    proj_fi(t0, zs, w_f + HH, b_f + 1, w_i + HH, b_i + 1, start, g1, i1);
    grid_barrier(bar + 1);

    // ---- P2 ----
    attn_row(t0, k1b, v1b, qs, os, g1, i1, hs);
    __syncthreads();
    ff_block(hs, es, wff_p + 8192, b_ff + HH, zs);
    __syncthreads();
    dense128(t0, zs, wout_p, b_out, out, (float*)0);
}

extern "C" void kernel_launch(void* const* d_in, const int* in_sizes, int n_in,
                              void* d_out, int out_size, void* d_ws, size_t ws_size,
                              hipStream_t stream) {
    const float* emb   = (const float*)d_in[0];
    const int*   start = (const int*)  d_in[1];
    const float* w_in  = (const float*)d_in[2];
    const float* b_in  = (const float*)d_in[3];
    const float* w_out = (const float*)d_in[4];
    const float* b_out = (const float*)d_in[5];
    const float* w_f   = (const float*)d_in[6];
    const float* b_f   = (const float*)d_in[7];
    const float* w_i   = (const float*)d_in[8];
    const float* b_i   = (const float*)d_in[9];
    const float* w_v   = (const float*)d_in[10];
    const float* b_v   = (const float*)d_in[11];
    const float* w_q   = (const float*)d_in[12];
    const float* b_q   = (const float*)d_in[13];
    const float* w_k   = (const float*)d_in[14];
    const float* b_k   = (const float*)d_in[15];
    const float* w_o   = (const float*)d_in[16];
    const float* b_o   = (const float*)d_in[17];
    const float* w_ff  = (const float*)d_in[18];
    const float* b_ff  = (const float*)d_in[19];
    float* out = (float*)d_out;

    unsigned* bar = (unsigned*)d_ws;            // 16 counters, zeroed by prep
    float* ws = (float*)d_ws + 64;
    float* k0b = ws; ws += TT * HH;
    float* v0b = ws; ws += TT * HH;
    float* k1b = ws; ws += TT * HH;
    float* v1b = ws; ws += TT * HH;
    float* g0  = ws; ws += TT;
    float* i0  = ws; ws += TT;
    float* g1  = ws; ws += TT;
    float* i1  = ws; ws += TT;
    float4* win_p  = (float4*)ws; ws += 16384;   // 4096 float4
    float4* wout_p = (float4*)ws; ws += 16384;   // 4096 float4
    float4* wcat   = (float4*)ws; ws += 131072;  // 32768 float4 (2 layers)
    float4* wff_p  = (float4*)ws; ws += 65536;   // 16384 float4 (2 layers)

    prep_kernel<<<dim3(224), dim3(256), 0, stream>>>(
        w_in, w_out, w_v, w_q, w_k, w_o, w_ff, win_p, wout_p, wcat, wff_p, bar);
    mega_kernel<<<dim3(NBLK), dim3(512), 0, stream>>>(
        emb, start, win_p, b_in, wcat,
        b_v, b_q, b_k, b_o, w_f, b_f, w_i, b_i,
        wff_p, b_ff, wout_p, b_out,
        k0b, v0b, k1b, v1b, g0, i0, g1, i1,
        bar, out);
}